// Round 10
// baseline (186.420 us; speedup 1.0000x reference)
//
#include <hip/hip_runtime.h>
#include <stdint.h>

typedef __attribute__((ext_vector_type(8))) short short8;
typedef __attribute__((ext_vector_type(4))) float f32x4;

static constexpr int D = 128;

static __device__ __forceinline__ unsigned short f32_to_bf16(float f) {
  unsigned int u = __builtin_bit_cast(unsigned int, f);
  return (unsigned short)((u + 0x7FFFu + ((u >> 16) & 1u)) >> 16);
}
static __device__ __forceinline__ float bf16_to_f32(unsigned short h) {
  return __builtin_bit_cast(float, ((unsigned int)h) << 16);
}

// Fused prep (one dispatch): feat hi/lo split + norms (blocks [0,NBF); first
// 33 also zero sum_e/sum_d/done), proto split + norms + padding
// ([NBF,NBF+NBP)), single-block histogram (writes cc fully, no pre-zero needed).
extern "C" __global__ __launch_bounds__(256) void k_prep(
    const float* __restrict__ x, const float* __restrict__ pf,
    const int* __restrict__ plab_in,
    unsigned short* __restrict__ xh, unsigned short* __restrict__ xl,
    unsigned short* __restrict__ ph, unsigned short* __restrict__ pl,
    float* __restrict__ x2, float* __restrict__ p2,
    int* __restrict__ plab, int* __restrict__ cc,
    unsigned int* __restrict__ zeroreg, int zwords,
    int B, int P, int NBF, int NBP) {
  __shared__ int hist[256];
  const int bid = blockIdx.x;
  const int tid = threadIdx.x;
  const int wid = tid >> 6, lane = tid & 63;

  if (bid < NBF) {
    const int b = bid * 4 + wid;                 // NBF*4 == B exactly
    const float2 f = *(const float2*)(x + (size_t)b * D + lane * 2);
    const unsigned short h0 = f32_to_bf16(f.x), h1 = f32_to_bf16(f.y);
    const unsigned short l0 = f32_to_bf16(f.x - bf16_to_f32(h0));
    const unsigned short l1 = f32_to_bf16(f.y - bf16_to_f32(h1));
    ((unsigned int*)xh)[(size_t)b * 64 + lane] = (unsigned int)h0 | ((unsigned int)h1 << 16);
    ((unsigned int*)xl)[(size_t)b * 64 + lane] = (unsigned int)l0 | ((unsigned int)l1 << 16);
    float s = fmaf(f.x, f.x, f.y * f.y);
    #pragma unroll
    for (int m = 1; m < 64; m <<= 1) s += __shfl_xor(s, m, 64);
    if (lane == 0) x2[b] = s;
    const int w = bid * 256 + tid;               // zero sums/done (33 blocks cover)
    if (w < zwords) zeroreg[w] = 0u;
  } else if (bid < NBF + NBP) {
    const int r = (bid - NBF) * 4 + wid;         // NBP*4 == P_pad
    if (r < P) {
      const float2 f = *(const float2*)(pf + (size_t)r * D + lane * 2);
      const unsigned short h0 = f32_to_bf16(f.x), h1 = f32_to_bf16(f.y);
      const unsigned short l0 = f32_to_bf16(f.x - bf16_to_f32(h0));
      const unsigned short l1 = f32_to_bf16(f.y - bf16_to_f32(h1));
      ((unsigned int*)ph)[(size_t)r * 64 + lane] = (unsigned int)h0 | ((unsigned int)h1 << 16);
      ((unsigned int*)pl)[(size_t)r * 64 + lane] = (unsigned int)l0 | ((unsigned int)l1 << 16);
      float s = fmaf(f.x, f.x, f.y * f.y);
      #pragma unroll
      for (int m = 1; m < 64; m <<= 1) s += __shfl_xor(s, m, 64);
      if (lane == 0) { p2[r] = s; plab[r] = plab_in[r]; }
    } else {
      // pad rows: zero features, huge norm -> exp underflows to 0; label -1 never matches
      ((unsigned int*)ph)[(size_t)r * 64 + lane] = 0u;
      ((unsigned int*)pl)[(size_t)r * 64 + lane] = 0u;
      if (lane == 0) { p2[r] = 1e30f; plab[r] = -1; }
    }
  } else {
    // single histogram block: LDS atomics, then full overwrite of cc (no pre-zero)
    hist[tid] = 0;
    __syncthreads();
    for (int r = tid; r < P; r += 256) atomicAdd(&hist[plab_in[r] & 255], 1);
    __syncthreads();
    cc[tid] = hist[tid];
  }
}

// Main fused kernel (round-6 proven geometry): grid (nrt=32 rowtiles, nph=24
// phases). Per block: 4 waves x 32 feature rows (A-frags in regs), 32-row proto
// tiles staged to a single 16KB LDS buffer (pre-swizzled source, linear
// global_load_lds dest, XOR'd ds_read_b128), stage -> sync -> compute -> sync.
// Epilogue fused: sqrt(builtin) + exp + masked add; per-row global atomics.
// FUSED FINISH: last block per rowtile (done-counter) computes final loss for
// its 128 rows via device-coherent atomic reads (replaces k_combine dispatch).
extern "C" __global__ __launch_bounds__(256, 4) void k_dce_main(
    const unsigned short* __restrict__ xh, const unsigned short* __restrict__ xl,
    const unsigned short* __restrict__ ph, const unsigned short* __restrict__ pl,
    const float* __restrict__ x2, const float* __restrict__ p2,
    const int* __restrict__ lab, const int* __restrict__ plab,
    float* __restrict__ sum_e, float* __restrict__ sum_d,
    int* __restrict__ done, const int* __restrict__ cc,
    float* __restrict__ out, int B, int NT) {
  __shared__ unsigned char lds[16384];  // 8KB hi + 8KB lo
  __shared__ int iam_last;

  const int tid = threadIdx.x;
  const int wid = tid >> 6;
  const int lane = tid & 63;
  const int l15 = lane & 15;
  const int lg = lane >> 4;

  const int rt = blockIdx.x;            // rowtile
  const int phase = blockIdx.y;
  const int nph = gridDim.y;
  const int rb = rt * 128 + wid * 32;

  // A fragments: 2 rowsets x 4 K-chunks, hi and lo (row = lane&15, k = (lane>>4)*8+j)
  short8 ah[2][4], al[2][4];
  #pragma unroll
  for (int rs = 0; rs < 2; ++rs) {
    int row = rb + rs * 16 + l15; if (row >= B) row = B - 1;
    #pragma unroll
    for (int c = 0; c < 4; ++c) {
      const int k = c * 32 + lg * 8;
      ah[rs][c] = *(const short8*)(xh + (size_t)row * D + k);
      al[rs][c] = *(const short8*)(xl + (size_t)row * D + k);
    }
  }

  // per-lane output-row metadata (C layout: row = (lane>>4)*4 + reg)
  float x2v[2][4]; int labv[2][4];
  #pragma unroll
  for (int rs = 0; rs < 2; ++rs) {
    #pragma unroll
    for (int r = 0; r < 4; ++r) {
      int row = rb + rs * 16 + lg * 4 + r; if (row >= B) row = B - 1;
      x2v[rs][r] = x2[row];
      labv[rs][r] = lab[row];
    }
  }

  float acc_e[2][4] = {{0.f,0.f,0.f,0.f},{0.f,0.f,0.f,0.f}};
  float acc_d[2][4] = {{0.f,0.f,0.f,0.f},{0.f,0.f,0.f,0.f}};

  // staging geometry: 16 wave-loads of 1024B cover the 16KB (hi+lo) tile; 4/wave.
  // LDS dest linear (lane*16 appended by HW); source pre-swizzled so reads at
  // byte ^ ((row&7)<<4) return linear data (bank-balanced ds_read_b128).
  const unsigned char* srcb[4];
  unsigned char* dstb[4];
  #pragma unroll
  for (int q = 0; q < 4; ++q) {
    const int jj = wid * 4 + q;
    const int type = jj >> 3, ch = jj & 7;
    const int r = ch * 4 + lg;
    const int srcoff = r * 256 + ((l15 * 16) ^ ((r & 7) << 4));
    srcb[q] = (const unsigned char*)(type ? pl : ph) + srcoff;
    dstb[q] = &lds[type * 8192 + ch * 1024];
  }

  for (int tp = phase; tp < NT; tp += nph) {
    const size_t toff = (size_t)tp * 8192;
    #pragma unroll
    for (int q = 0; q < 4; ++q) {
      __builtin_amdgcn_global_load_lds(
          (const __attribute__((address_space(1))) void*)(srcb[q] + toff),
          (__attribute__((address_space(3))) void*)dstb[q], 16, 0, 0);
    }
    // hoisted per-tile column metadata (issued before the drain barrier)
    const int col0 = tp * 32 + l15;
    const float p2v0 = p2[col0], p2v1 = p2[col0 + 16];
    const int plv0 = plab[col0], plv1 = plab[col0 + 16];
    __syncthreads();  // drains vmcnt before barrier -> tile visible

    #pragma unroll
    for (int s = 0; s < 2; ++s) {
      f32x4 acc0 = {0.f,0.f,0.f,0.f}, acc1 = {0.f,0.f,0.f,0.f};
      const int pr = s * 16 + l15;        // proto row within tile (B-frag col)
      const int rowbyte = pr * 256;
      const int swz = (pr & 7) << 4;
      #pragma unroll
      for (int c = 0; c < 4; ++c) {
        const int off = rowbyte + ((c * 64 + lg * 16) ^ swz);
        const short8 bh = *(const short8*)&lds[off];
        const short8 bl = *(const short8*)&lds[8192 + off];
        acc0 = __builtin_amdgcn_mfma_f32_16x16x32_bf16(ah[0][c], bh, acc0, 0, 0, 0);
        acc1 = __builtin_amdgcn_mfma_f32_16x16x32_bf16(ah[1][c], bh, acc1, 0, 0, 0);
        acc0 = __builtin_amdgcn_mfma_f32_16x16x32_bf16(ah[0][c], bl, acc0, 0, 0, 0);
        acc1 = __builtin_amdgcn_mfma_f32_16x16x32_bf16(ah[1][c], bl, acc1, 0, 0, 0);
        acc0 = __builtin_amdgcn_mfma_f32_16x16x32_bf16(al[0][c], bh, acc0, 0, 0, 0);
        acc1 = __builtin_amdgcn_mfma_f32_16x16x32_bf16(al[1][c], bh, acc1, 0, 0, 0);
      }
      const float p2c = s ? p2v1 : p2v0;
      const int plc = s ? plv1 : plv0;
      #pragma unroll
      for (int rs = 0; rs < 2; ++rs) {
        const f32x4 a = rs ? acc1 : acc0;
        #pragma unroll
        for (int r = 0; r < 4; ++r) {
          const float S = a[r];
          const float d2 = fmaxf(x2v[rs][r] + p2c - 2.0f * S, 1e-12f);
          const float dist = __builtin_amdgcn_sqrtf(d2);  // raw v_sqrt_f32, ~1ulp
          acc_e[rs][r] += __expf(-dist);                       // GAMMA = 1
          acc_d[rs][r] += (plc == labv[rs][r]) ? dist : 0.0f;  // masked dist sum
        }
      }
    }
    __syncthreads();  // done reading tile before next stage overwrites
  }

  // reduce over the 16 lanes sharing each output row, then one atomic per row
  #pragma unroll
  for (int rs = 0; rs < 2; ++rs) {
    #pragma unroll
    for (int r = 0; r < 4; ++r) {
      float e = acc_e[rs][r], d = acc_d[rs][r];
      #pragma unroll
      for (int m = 1; m < 16; m <<= 1) {
        e += __shfl_xor(e, m, 64);
        d += __shfl_xor(d, m, 64);
      }
      if (l15 == 0) {
        const int row = rb + rs * 16 + lg * 4 + r;
        if (row < B) {
          atomicAdd(&sum_e[row], e);
          atomicAdd(&sum_d[row], d);
        }
      }
    }
  }

  // fused finish: last block of this rowtile finalizes its 128 rows
  __threadfence();                       // release our sum atomics
  __syncthreads();
  if (tid == 0) iam_last = (atomicAdd(&done[rt], 1) == nph - 1) ? 1 : 0;
  __syncthreads();
  if (iam_last) {
    __threadfence();                     // acquire other blocks' sums
    if (tid < 128) {
      const int row = rt * 128 + tid;
      if (row < B) {
        const float se = atomicAdd(&sum_e[row], 0.0f);   // device-coherent read
        const float sd = atomicAdd(&sum_d[row], 0.0f);
        const float cnt = (float)cc[lab[row] & 255];
        out[row] = cnt * __logf(se) + sd;
      }
    }
  }
}

extern "C" void kernel_launch(void* const* d_in, const int* in_sizes, int n_in,
                              void* d_out, int out_size, void* d_ws, size_t ws_size,
                              hipStream_t stream) {
  (void)n_in; (void)out_size; (void)ws_size;
  const float* feat = (const float*)d_in[0];
  const int* lab = (const int*)d_in[1];
  const float* pf = (const float*)d_in[2];
  const int* plab_in = (const int*)d_in[3];
  const int B = in_sizes[0] / D;        // 4096
  const int P = in_sizes[3];            // 10000
  const int P_pad = (P + 31) & ~31;     // 10016
  const int NT = P_pad / 32;            // 313
  const int nrt = B / 128;              // 32 rowtiles

  uint8_t* ws = (uint8_t*)d_ws;
  size_t cur = 0;
  auto carve = [&](size_t bytes) {
    size_t off = cur;
    cur = (cur + bytes + 255) & ~(size_t)255;
    return off;
  };
  unsigned short* xh = (unsigned short*)(ws + carve((size_t)B * D * 2));
  unsigned short* xl = (unsigned short*)(ws + carve((size_t)B * D * 2));
  unsigned short* ph = (unsigned short*)(ws + carve((size_t)P_pad * D * 2));
  unsigned short* pl = (unsigned short*)(ws + carve((size_t)P_pad * D * 2));
  float* x2 = (float*)(ws + carve((size_t)B * 4));
  float* p2 = (float*)(ws + carve((size_t)P_pad * 4));
  int* plab = (int*)(ws + carve((size_t)P_pad * 4));
  int* cc = (int*)(ws + carve(256 * 4));          // fully written by hist block
  // zero region: sum_e(B) | sum_d(B) | done(nrt) -- zeroed inside k_prep
  float* sum_e = (float*)(ws + carve((size_t)(2 * B + nrt) * 4));
  float* sum_d = sum_e + B;
  int* done = (int*)(sum_d + B);
  float* out = (float*)d_out;

  const int zwords = 2 * B + nrt;       // 8224 ints
  const int NBF = B / 4;                // 1024 (>= ceil(zwords/256)=33)
  const int NBP = P_pad / 4;            // 2504
  k_prep<<<dim3(NBF + NBP + 1), dim3(256), 0, stream>>>(
      feat, pf, plab_in, xh, xl, ph, pl, x2, p2, plab, cc,
      (unsigned int*)sum_e, zwords, B, P, NBF, NBP);

  dim3 grid(nrt, 24);                   // round-6 proven geometry: 768 blocks
  k_dce_main<<<grid, dim3(256), 0, stream>>>(xh, xl, ph, pl, x2, p2, lab, plab,
                                             sum_e, sum_d, done, cc, out, B, NT);
}

// Round 13
// 106.758 us; speedup vs baseline: 1.7462x; 1.7462x over previous
//
#include <hip/hip_runtime.h>
#include <stdint.h>

typedef __attribute__((ext_vector_type(8))) short short8;
typedef __attribute__((ext_vector_type(4))) float f32x4;

static constexpr int D = 128;

static __device__ __forceinline__ unsigned short f32_to_bf16(float f) {
  unsigned int u = __builtin_bit_cast(unsigned int, f);
  return (unsigned short)((u + 0x7FFFu + ((u >> 16) & 1u)) >> 16);
}
static __device__ __forceinline__ float bf16_to_f32(unsigned short h) {
  return __builtin_bit_cast(float, ((unsigned int)h) << 16);
}

// Fused prep (one dispatch): feat hi/lo split + norms (blocks [0,NBF); first
// 32 also zero sum_e/sum_d), proto split + norms + padding ([NBF,NBF+NBP)),
// single-block histogram (writes cc fully, no pre-zero needed).
extern "C" __global__ __launch_bounds__(256) void k_prep(
    const float* __restrict__ x, const float* __restrict__ pf,
    const int* __restrict__ plab_in,
    unsigned short* __restrict__ xh, unsigned short* __restrict__ xl,
    unsigned short* __restrict__ ph, unsigned short* __restrict__ pl,
    float* __restrict__ x2, float* __restrict__ p2,
    int* __restrict__ plab, int* __restrict__ cc,
    unsigned int* __restrict__ zeroreg, int zwords,
    int B, int P, int NBF, int NBP) {
  __shared__ int hist[256];
  const int bid = blockIdx.x;
  const int tid = threadIdx.x;
  const int wid = tid >> 6, lane = tid & 63;

  if (bid < NBF) {
    const int b = bid * 4 + wid;                 // NBF*4 == B exactly
    const float2 f = *(const float2*)(x + (size_t)b * D + lane * 2);
    const unsigned short h0 = f32_to_bf16(f.x), h1 = f32_to_bf16(f.y);
    const unsigned short l0 = f32_to_bf16(f.x - bf16_to_f32(h0));
    const unsigned short l1 = f32_to_bf16(f.y - bf16_to_f32(h1));
    ((unsigned int*)xh)[(size_t)b * 64 + lane] = (unsigned int)h0 | ((unsigned int)h1 << 16);
    ((unsigned int*)xl)[(size_t)b * 64 + lane] = (unsigned int)l0 | ((unsigned int)l1 << 16);
    float s = fmaf(f.x, f.x, f.y * f.y);
    #pragma unroll
    for (int m = 1; m < 64; m <<= 1) s += __shfl_xor(s, m, 64);
    if (lane == 0) x2[b] = s;
    const int w = bid * 256 + tid;               // zero sums (32 blocks cover)
    if (w < zwords) zeroreg[w] = 0u;
  } else if (bid < NBF + NBP) {
    const int r = (bid - NBF) * 4 + wid;         // NBP*4 == P_pad
    if (r < P) {
      const float2 f = *(const float2*)(pf + (size_t)r * D + lane * 2);
      const unsigned short h0 = f32_to_bf16(f.x), h1 = f32_to_bf16(f.y);
      const unsigned short l0 = f32_to_bf16(f.x - bf16_to_f32(h0));
      const unsigned short l1 = f32_to_bf16(f.y - bf16_to_f32(h1));
      ((unsigned int*)ph)[(size_t)r * 64 + lane] = (unsigned int)h0 | ((unsigned int)h1 << 16);
      ((unsigned int*)pl)[(size_t)r * 64 + lane] = (unsigned int)l0 | ((unsigned int)l1 << 16);
      float s = fmaf(f.x, f.x, f.y * f.y);
      #pragma unroll
      for (int m = 1; m < 64; m <<= 1) s += __shfl_xor(s, m, 64);
      if (lane == 0) { p2[r] = s; plab[r] = plab_in[r]; }
    } else {
      // pad rows: zero features, huge norm -> exp underflows to 0; label -1 never matches
      ((unsigned int*)ph)[(size_t)r * 64 + lane] = 0u;
      ((unsigned int*)pl)[(size_t)r * 64 + lane] = 0u;
      if (lane == 0) { p2[r] = 1e30f; plab[r] = -1; }
    }
  } else {
    // single histogram block: LDS atomics, then full overwrite of cc (no pre-zero)
    hist[tid] = 0;
    __syncthreads();
    for (int r = tid; r < P; r += 256) atomicAdd(&hist[plab_in[r] & 255], 1);
    __syncthreads();
    cc[tid] = hist[tid];
  }
}

// Main fused kernel — EXACT round-6 measured-best structure (62us, FETCH 21MB):
// grid (nrt=32 rowtiles, 24 phases), launch_bounds(256,3), single 16KB LDS
// buffer, stage -> sync -> compute -> sync. No fences, no done-counters
// (round-10 lesson: per-block __threadfence invalidates L2 mid-flight ->
// re-fetch storm, 2x slowdown). Deltas vs r6, both evidence-backed:
// builtin sqrt (r7: halved VALU cycles) and pre-barrier p2/plab hoist.
extern "C" __global__ __launch_bounds__(256, 3) void k_dce_main(
    const unsigned short* __restrict__ xh, const unsigned short* __restrict__ xl,
    const unsigned short* __restrict__ ph, const unsigned short* __restrict__ pl,
    const float* __restrict__ x2, const float* __restrict__ p2,
    const int* __restrict__ lab, const int* __restrict__ plab,
    float* __restrict__ sum_e, float* __restrict__ sum_d,
    int B, int NT) {
  __shared__ unsigned char lds[16384];  // 8KB hi + 8KB lo

  const int tid = threadIdx.x;
  const int wid = tid >> 6;
  const int lane = tid & 63;
  const int l15 = lane & 15;
  const int lg = lane >> 4;

  const int rb = blockIdx.x * 128 + wid * 32;
  const int phase = blockIdx.y;
  const int nph = gridDim.y;

  // A fragments: 2 rowsets x 4 K-chunks, hi and lo (row = lane&15, k = (lane>>4)*8+j)
  short8 ah[2][4], al[2][4];
  #pragma unroll
  for (int rs = 0; rs < 2; ++rs) {
    int row = rb + rs * 16 + l15; if (row >= B) row = B - 1;
    #pragma unroll
    for (int c = 0; c < 4; ++c) {
      const int k = c * 32 + lg * 8;
      ah[rs][c] = *(const short8*)(xh + (size_t)row * D + k);
      al[rs][c] = *(const short8*)(xl + (size_t)row * D + k);
    }
  }

  // per-lane output-row metadata (C layout: row = (lane>>4)*4 + reg)
  float x2v[2][4]; int labv[2][4];
  #pragma unroll
  for (int rs = 0; rs < 2; ++rs) {
    #pragma unroll
    for (int r = 0; r < 4; ++r) {
      int row = rb + rs * 16 + lg * 4 + r; if (row >= B) row = B - 1;
      x2v[rs][r] = x2[row];
      labv[rs][r] = lab[row];
    }
  }

  float acc_e[2][4] = {{0.f,0.f,0.f,0.f},{0.f,0.f,0.f,0.f}};
  float acc_d[2][4] = {{0.f,0.f,0.f,0.f},{0.f,0.f,0.f,0.f}};

  // staging geometry: 16 wave-loads of 1024B cover the 16KB (hi+lo) tile; 4/wave.
  // LDS dest linear (lane*16 appended by HW); source pre-swizzled so reads at
  // byte ^ ((row&7)<<4) return linear data (bank-balanced ds_read_b128).
  const unsigned char* srcb[4];
  unsigned char* dstb[4];
  #pragma unroll
  for (int q = 0; q < 4; ++q) {
    const int jj = wid * 4 + q;
    const int type = jj >> 3, ch = jj & 7;
    const int r = ch * 4 + lg;
    const int srcoff = r * 256 + ((l15 * 16) ^ ((r & 7) << 4));
    srcb[q] = (const unsigned char*)(type ? pl : ph) + srcoff;
    dstb[q] = &lds[type * 8192 + ch * 1024];
  }

  for (int tp = phase; tp < NT; tp += nph) {
    const size_t toff = (size_t)tp * 8192;
    #pragma unroll
    for (int q = 0; q < 4; ++q) {
      __builtin_amdgcn_global_load_lds(
          (const __attribute__((address_space(1))) void*)(srcb[q] + toff),
          (__attribute__((address_space(3))) void*)dstb[q], 16, 0, 0);
    }
    // hoisted per-tile column metadata: issued before the drain barrier,
    // completes during it -> off the epilogue critical path
    const int col0 = tp * 32 + l15;
    const float p2v0 = p2[col0], p2v1 = p2[col0 + 16];
    const int plv0 = plab[col0], plv1 = plab[col0 + 16];
    __syncthreads();  // drains vmcnt -> tile visible

    #pragma unroll
    for (int s = 0; s < 2; ++s) {
      f32x4 acc0 = {0.f,0.f,0.f,0.f}, acc1 = {0.f,0.f,0.f,0.f};
      const int pr = s * 16 + l15;        // proto row within tile (B-frag col)
      const int rowbyte = pr * 256;
      const int swz = (pr & 7) << 4;
      #pragma unroll
      for (int c = 0; c < 4; ++c) {
        const int off = rowbyte + ((c * 64 + lg * 16) ^ swz);
        const short8 bh = *(const short8*)&lds[off];
        const short8 bl = *(const short8*)&lds[8192 + off];
        acc0 = __builtin_amdgcn_mfma_f32_16x16x32_bf16(ah[0][c], bh, acc0, 0, 0, 0);
        acc1 = __builtin_amdgcn_mfma_f32_16x16x32_bf16(ah[1][c], bh, acc1, 0, 0, 0);
        acc0 = __builtin_amdgcn_mfma_f32_16x16x32_bf16(ah[0][c], bl, acc0, 0, 0, 0);
        acc1 = __builtin_amdgcn_mfma_f32_16x16x32_bf16(ah[1][c], bl, acc1, 0, 0, 0);
        acc0 = __builtin_amdgcn_mfma_f32_16x16x32_bf16(al[0][c], bh, acc0, 0, 0, 0);
        acc1 = __builtin_amdgcn_mfma_f32_16x16x32_bf16(al[1][c], bh, acc1, 0, 0, 0);
      }
      const float p2c = s ? p2v1 : p2v0;
      const int plc = s ? plv1 : plv0;
      #pragma unroll
      for (int rs = 0; rs < 2; ++rs) {
        const f32x4 a = rs ? acc1 : acc0;
        #pragma unroll
        for (int r = 0; r < 4; ++r) {
          const float S = a[r];
          const float d2 = fmaxf(x2v[rs][r] + p2c - 2.0f * S, 1e-12f);
          const float dist = __builtin_amdgcn_sqrtf(d2);  // raw v_sqrt_f32, ~1ulp
          acc_e[rs][r] += __expf(-dist);                       // GAMMA = 1
          acc_d[rs][r] += (plc == labv[rs][r]) ? dist : 0.0f;  // masked dist sum
        }
      }
    }
    __syncthreads();  // done reading tile before next stage overwrites
  }

  // reduce over the 16 lanes sharing each output row, then one atomic per row
  #pragma unroll
  for (int rs = 0; rs < 2; ++rs) {
    #pragma unroll
    for (int r = 0; r < 4; ++r) {
      float e = acc_e[rs][r], d = acc_d[rs][r];
      #pragma unroll
      for (int m = 1; m < 16; m <<= 1) {
        e += __shfl_xor(e, m, 64);
        d += __shfl_xor(d, m, 64);
      }
      if (l15 == 0) {
        const int row = rb + rs * 16 + lg * 4 + r;
        if (row < B) {
          atomicAdd(&sum_e[row], e);
          atomicAdd(&sum_d[row], d);
        }
      }
    }
  }
}

extern "C" __global__ __launch_bounds__(256) void k_combine(
    const float* __restrict__ sum_e, const float* __restrict__ sum_d,
    const int* __restrict__ lab, const int* __restrict__ cc,
    float* __restrict__ out, int B) {
  const int b = blockIdx.x * 256 + threadIdx.x;
  if (b < B) {
    const float cnt = (float)cc[lab[b] & 255];
    out[b] = cnt * __logf(sum_e[b]) + sum_d[b];
  }
}

extern "C" void kernel_launch(void* const* d_in, const int* in_sizes, int n_in,
                              void* d_out, int out_size, void* d_ws, size_t ws_size,
                              hipStream_t stream) {
  (void)n_in; (void)out_size; (void)ws_size;
  const float* feat = (const float*)d_in[0];
  const int* lab = (const int*)d_in[1];
  const float* pf = (const float*)d_in[2];
  const int* plab_in = (const int*)d_in[3];
  const int B = in_sizes[0] / D;        // 4096
  const int P = in_sizes[3];            // 10000
  const int P_pad = (P + 31) & ~31;     // 10016
  const int NT = P_pad / 32;            // 313
  const int nrt = B / 128;              // 32 rowtiles

  uint8_t* ws = (uint8_t*)d_ws;
  size_t cur = 0;
  auto carve = [&](size_t bytes) {
    size_t off = cur;
    cur = (cur + bytes + 255) & ~(size_t)255;
    return off;
  };
  unsigned short* xh = (unsigned short*)(ws + carve((size_t)B * D * 2));
  unsigned short* xl = (unsigned short*)(ws + carve((size_t)B * D * 2));
  unsigned short* ph = (unsigned short*)(ws + carve((size_t)P_pad * D * 2));
  unsigned short* pl = (unsigned short*)(ws + carve((size_t)P_pad * D * 2));
  float* x2 = (float*)(ws + carve((size_t)B * 4));
  float* p2 = (float*)(ws + carve((size_t)P_pad * 4));
  int* plab = (int*)(ws + carve((size_t)P_pad * 4));
  int* cc = (int*)(ws + carve(256 * 4));          // fully written by hist block
  // zero region: sum_e(B) | sum_d(B) -- zeroed inside k_prep
  float* sum_e = (float*)(ws + carve((size_t)(2 * B) * 4));
  float* sum_d = sum_e + B;
  float* out = (float*)d_out;

  const int zwords = 2 * B;             // 8192 ints (32 prep blocks cover)
  const int NBF = B / 4;                // 1024
  const int NBP = P_pad / 4;            // 2504
  k_prep<<<dim3(NBF + NBP + 1), dim3(256), 0, stream>>>(
      feat, pf, plab_in, xh, xl, ph, pl, x2, p2, plab, cc,
      (unsigned int*)sum_e, zwords, B, P, NBF, NBP);

  dim3 grid(nrt, 24);                   // round-6 proven geometry: 768 blocks
  k_dce_main<<<grid, dim3(256), 0, stream>>>(xh, xl, ph, pl, x2, p2, lab, plab,
                                             sum_e, sum_d, B, NT);
  k_combine<<<dim3((B + 255) / 256), dim3(256), 0, stream>>>(sum_e, sum_d, lab, cc, out, B);
}